// Round 4
// baseline (282.075 us; speedup 1.0000x reference)
//
#include <hip/hip_runtime.h>
#include <hip/hip_cooperative_groups.h>
#include <hip/hip_bf16.h>
#include <math.h>
#include <stdint.h>

namespace cg = cooperative_groups;

// ---------------------------------------------------------------------------
// MultiSimilarityLoss on MI355X.
//   x: [B=4096, D=1024] fp32 (L2-normalized rows), labels: [B] int32
//   out: scalar fp32 = mean of mined multi-similarity loss
// Pipeline (R5):
//   K0: memset gmin=0xFF.., gmax=0
//   K1: x fp32 -> bf16
//   K2: ONE cooperative kernel, full 1024-block grid (4 blocks/CU exact):
//       GEMM (128x128, BK=64 single-buffer, T2 swizzle) -> acc in regs;
//       phase A: per-row min_pos/max_neg, LDS-combined, atomicMin/Max;
//       grid.sync();
//       phase B: mined exp sums FROM LIVE acc -> per-(row,colblk) partials.
//       Fallback (coop launch refused): same code as two non-coop passes.
//   K3: rowfinal (sum 32 partials, log1p) -> rowbuf;  K4: reduce -> out.
// R4 post-mortem: GEMM is latency-bound (MfmaUtil 8%, HBM 8%, occ 7.5%).
//   Triangular grid = 2 blocks/CU starved TLP; m97 anchor needs 4 blocks/CU.
//   Full grid + register-carried acc across grid.sync computes GEMM once.
// ---------------------------------------------------------------------------

#define THRESH    0.5f
#define MARGIN    0.1f
#define SCALE_POS 2.0f
#define SCALE_NEG 40.0f
#define POS_CAP   (1.0f - 1e-5f)

typedef __bf16 bf16x8 __attribute__((ext_vector_type(8)));
typedef float  f32x4  __attribute__((ext_vector_type(4)));

__device__ __forceinline__ uint16_t f2bf(float f) {
  union { float f; uint32_t u; } v; v.f = f;
  uint32_t u = v.u;
  u += 0x7FFFu + ((u >> 16) & 1u);
  return (uint16_t)(u >> 16);
}

__device__ __forceinline__ uint32_t fenc(float f) {
  union { float f; uint32_t u; } v; v.f = f;
  return (v.u & 0x80000000u) ? ~v.u : (v.u ^ 0x80000000u);
}
__device__ __forceinline__ float fdec(uint32_t k) {
  union { float f; uint32_t u; } v;
  v.u = (k & 0x80000000u) ? (k ^ 0x80000000u) : ~k;
  return v.f;
}

__global__ __launch_bounds__(256) void cvt_bf16_kernel(
    const float* __restrict__ x, uint16_t* __restrict__ y, int n) {
  int i = (blockIdx.x * 256 + threadIdx.x) * 4;
  if (i + 3 < n) {
    float4 v = *(const float4*)(x + i);
    ushort4 o;
    o.x = f2bf(v.x); o.y = f2bf(v.y); o.z = f2bf(v.z); o.w = f2bf(v.w);
    *(ushort4*)(y + i) = o;
  }
}

#if defined(__has_builtin)
#if __has_builtin(__builtin_amdgcn_global_load_lds)
#define HAVE_GLL 1
#endif
#endif

__device__ __forceinline__ void stage16(const uint16_t* g, uint16_t* lds_wave_base, int lane) {
#ifdef HAVE_GLL
  __builtin_amdgcn_global_load_lds(
      (const __attribute__((address_space(1))) void*)g,
      (__attribute__((address_space(3))) void*)lds_wave_base, 16, 0, 0);
#else
  *(uint4*)(lds_wave_base + lane * 8) = *(const uint4*)g;
#endif
}

// MODE 0: coop single-pass (stats, grid sync, sums)
// MODE 1: stats only     MODE 2: sums only (recompute GEMM) -- fallback path
template <int MODE>
__global__ __launch_bounds__(256, 4) void msl_kernel(
    const uint16_t* __restrict__ X, const int* __restrict__ labels,
    uint32_t* __restrict__ gmin, uint32_t* __restrict__ gmax,
    float* __restrict__ psum_part, float* __restrict__ nsum_part,
    int B, int D) {
  // LDS budget (4 blocks/CU => <= 40960 B): 32768 + 1024 + 1024 + 2048 = 36864
  __shared__ __align__(16) uint16_t sA[128 * 64];   // 16 KiB
  __shared__ __align__(16) uint16_t sB[128 * 64];   // 16 KiB
  __shared__ int   slabR[128], slabC[128];          // 1 KiB
  __shared__ float sStatMin[128], sStatMax[128];    // 1 KiB
  __shared__ float sRed0[2][128], sRed1[2][128];    // 2 KiB

  const int nblk = B >> 7;          // 32
  const int nb   = nblk * nblk;     // 1024

  // XCD chunk swizzle (nb % 8 == 0): XCD k owns contiguous tile indices
  int t = blockIdx.x;
  { const int cpx = nb >> 3; t = (t & 7) * cpx + (t >> 3); }
  const int bi = t / nblk;
  const int bj = t - bi * nblk;
  const int bm = bi * 128;
  const int bn = bj * 128;

  const int tid  = threadIdx.x;
  const int wave = tid >> 6;
  const int lane = tid & 63;
  const int waveM = wave >> 1, waveN = wave & 1;

  if (tid < 128) slabR[tid] = labels[bm + tid];
  else           slabC[tid - 128] = labels[bn + tid - 128];

  const uint16_t* gA = X + (size_t)bm * D;
  const uint16_t* gB = X + (size_t)bn * D;

  // staging map: LDS 16B-chunk idx = s*256 + tid; row = idx>>3 (128B rows);
  // global col byte = ((idx&7)<<4) ^ ((row&7)<<4)  (inverse T2 swizzle)
  int srcOff[4];
#pragma unroll
  for (int s = 0; s < 4; ++s) {
    const int idx = s * 256 + tid;
    const int row = idx >> 3;
    const int cb  = ((idx & 7) << 4) ^ ((row & 7) << 4);
    srcOff[s] = row * D + (cb >> 1);
  }

  const int fr = lane & 15;
  const int fq = lane >> 4;
  const int sw = (fr & 7) << 4;    // read-side swizzle (row&7 == fr&7)

  f32x4 acc[4][4] = {};

  const int NT = D >> 6;           // 16 K-tiles of 64
  for (int kt = 0; kt < NT; ++kt) {
    const int k0 = kt << 6;
#pragma unroll
    for (int s = 0; s < 4; ++s) {
      uint16_t* dA = sA + (s * 256 + wave * 64) * 8;
      uint16_t* dB = sB + (s * 256 + wave * 64) * 8;
      stage16(gA + srcOff[s] + k0, dA, lane);
      stage16(gB + srcOff[s] + k0, dB, lane);
    }
    __syncthreads();

    const char* tA = (const char*)sA;
    const char* tB = (const char*)sB;
#pragma unroll
    for (int kk = 0; kk < 2; ++kk) {
      const int cbyte = (kk * 64 + fq * 16) ^ sw;
      bf16x8 af[4], bfv[4];
#pragma unroll
      for (int mt = 0; mt < 4; ++mt) {
        const int rowa = waveM * 64 + mt * 16 + fr;
        af[mt] = *(const bf16x8*)(tA + rowa * 128 + cbyte);
      }
#pragma unroll
      for (int nt = 0; nt < 4; ++nt) {
        const int rowb = waveN * 64 + nt * 16 + fr;
        bfv[nt] = *(const bf16x8*)(tB + rowb * 128 + cbyte);
      }
#pragma unroll
      for (int mt = 0; mt < 4; ++mt)
#pragma unroll
        for (int nt = 0; nt < 4; ++nt)
          acc[mt][nt] = __builtin_amdgcn_mfma_f32_16x16x32_bf16(
              af[mt], bfv[nt], acc[mt][nt], 0, 0, 0);
    }
    __syncthreads();
  }

  const float INF = __builtin_inff();

  int lr[4][4];
#pragma unroll
  for (int mt = 0; mt < 4; ++mt)
#pragma unroll
    for (int r = 0; r < 4; ++r)
      lr[mt][r] = slabR[waveM * 64 + mt * 16 + fq * 4 + r];
  int lc[4];
#pragma unroll
  for (int nt = 0; nt < 4; ++nt) lc[nt] = slabC[waveN * 64 + nt * 16 + fr];

  // ---- phase A: per-row stats (row-side only; full grid covers all pairs) -
  if constexpr (MODE == 0 || MODE == 1) {
    float rmin[4][4], rmax[4][4];
#pragma unroll
    for (int mt = 0; mt < 4; ++mt)
#pragma unroll
      for (int r = 0; r < 4; ++r) { rmin[mt][r] = INF; rmax[mt][r] = -INF; }

#pragma unroll
    for (int mt = 0; mt < 4; ++mt) {
#pragma unroll
      for (int nt = 0; nt < 4; ++nt) {
        const int gcol = bn + waveN * 64 + nt * 16 + fr;
#pragma unroll
        for (int r = 0; r < 4; ++r) {
          const int grow = bm + waveM * 64 + mt * 16 + fq * 4 + r;
          const float s = acc[mt][nt][r];
          if (lr[mt][r] == lc[nt]) {
            if (grow != gcol && s < POS_CAP) rmin[mt][r] = fminf(rmin[mt][r], s);
          } else {
            rmax[mt][r] = fmaxf(rmax[mt][r], s);
          }
        }
      }
    }
#pragma unroll
    for (int mt = 0; mt < 4; ++mt)
#pragma unroll
      for (int r = 0; r < 4; ++r) {
#pragma unroll
        for (int m = 1; m < 16; m <<= 1) {
          rmin[mt][r] = fminf(rmin[mt][r], __shfl_xor(rmin[mt][r], m, 64));
          rmax[mt][r] = fmaxf(rmax[mt][r], __shfl_xor(rmax[mt][r], m, 64));
        }
      }
    if (fr == 0) {
#pragma unroll
      for (int mt = 0; mt < 4; ++mt)
#pragma unroll
        for (int r = 0; r < 4; ++r) {
          const int rloc = waveM * 64 + mt * 16 + fq * 4 + r;
          sRed0[waveN][rloc] = rmin[mt][r];
          sRed1[waveN][rloc] = rmax[mt][r];
        }
    }
    __syncthreads();
    if (tid < 128) {   // combine wave halves: 128 atomic pairs per block
      const float mn = fminf(sRed0[0][tid], sRed0[1][tid]);
      const float mx = fmaxf(sRed1[0][tid], sRed1[1][tid]);
      if (mn < INF)  atomicMin(&gmin[bm + tid], fenc(mn));
      if (mx > -INF) atomicMax(&gmax[bm + tid], fenc(mx));
    }
  }

  if constexpr (MODE == 1) return;

  if constexpr (MODE == 0) {
    cg::this_grid().sync();   // stats now globally complete; acc still live
  }

  // ---- phase B: mined exp sums from live accumulators ---------------------
  __syncthreads();           // safe reuse of sRed / sStat
  if (tid < 128) {
    const uint32_t km = gmin[bm + tid], kx = gmax[bm + tid];
    sStatMin[tid] = (km == 0xFFFFFFFFu) ? INF : fdec(km);
    sStatMax[tid] = (kx == 0u) ? -INF : fdec(kx);
  }
  __syncthreads();

  float lp[4][4] = {}, ln_[4][4] = {};
#pragma unroll
  for (int mt = 0; mt < 4; ++mt) {
#pragma unroll
    for (int r = 0; r < 4; ++r) {
      const int rloc = waveM * 64 + mt * 16 + fq * 4 + r;
      const int grow = bm + rloc;
      const float mR = sStatMin[rloc];   // min_pos
      const float xR = sStatMax[rloc];   // max_neg
      const int   la = lr[mt][r];
#pragma unroll
      for (int nt = 0; nt < 4; ++nt) {
        const int gcol = bn + waveN * 64 + nt * 16 + fr;
        const float s = acc[mt][nt][r];
        const bool same = (la == lc[nt]);
        if (same) {
          if (grow != gcol && s < POS_CAP && (s - MARGIN < xR))
            lp[mt][r] += __expf(-SCALE_POS * (s - THRESH));
        } else {
          if (s + MARGIN > mR)
            ln_[mt][r] += __expf(SCALE_NEG * (s - THRESH));
        }
      }
    }
  }
#pragma unroll
  for (int mt = 0; mt < 4; ++mt)
#pragma unroll
    for (int r = 0; r < 4; ++r) {
#pragma unroll
      for (int m = 1; m < 16; m <<= 1) {
        lp[mt][r]  += __shfl_xor(lp[mt][r],  m, 64);
        ln_[mt][r] += __shfl_xor(ln_[mt][r], m, 64);
      }
    }
  if (fr == 0) {
#pragma unroll
    for (int mt = 0; mt < 4; ++mt)
#pragma unroll
      for (int r = 0; r < 4; ++r) {
        const int rloc = waveM * 64 + mt * 16 + fq * 4 + r;
        sRed0[waveN][rloc] = lp[mt][r];
        sRed1[waveN][rloc] = ln_[mt][r];
      }
  }
  __syncthreads();
  if (tid < 128) {   // one deterministic partial per (row, colblock)
    const float p = sRed0[0][tid] + sRed0[1][tid];
    const float n = sRed1[0][tid] + sRed1[1][tid];
    psum_part[(size_t)(bm + tid) * nblk + bj] = p;
    nsum_part[(size_t)(bm + tid) * nblk + bj] = n;
  }
}

// ---- per-row final: sum partials (fixed order) + loss ----------------------
__global__ __launch_bounds__(256) void rowfinal_kernel(
    const uint32_t* __restrict__ gmin, const uint32_t* __restrict__ gmax,
    const float* __restrict__ psum_part, const float* __restrict__ nsum_part,
    float* __restrict__ rowbuf, int B, int nblk) {
  const int i = blockIdx.x * 256 + threadIdx.x;
  if (i >= B) return;
  float ps = 0.f, ns = 0.f;
  for (int q = 0; q < nblk; ++q) {
    ps += psum_part[(size_t)i * nblk + q];
    ns += nsum_part[(size_t)i * nblk + q];
  }
  const bool haspos = (gmin[i] != 0xFFFFFFFFu);
  const bool hasneg = (gmax[i] != 0u);
  const bool has_row = haspos && hasneg && (ps > 0.f) && (ns > 0.f);
  rowbuf[i] = has_row
      ? (log1pf(ps) * (1.0f / SCALE_POS) + log1pf(ns) * (1.0f / SCALE_NEG))
      : 0.f;
}

__global__ __launch_bounds__(256) void finalreduce_kernel(
    const float* __restrict__ rowbuf, float* __restrict__ out, int B) {
  __shared__ float red[4];
  const int tid  = threadIdx.x;
  const int wave = tid >> 6;
  const int lane = tid & 63;

  float s = 0.f;
  for (int j = tid * 4; j < B; j += 1024) {
    float4 v = *(const float4*)(rowbuf + j);
    s += v.x + v.y + v.z + v.w;
  }
#pragma unroll
  for (int m = 32; m > 0; m >>= 1) s += __shfl_xor(s, m, 64);
  if (lane == 0) red[wave] = s;
  __syncthreads();
  if (tid == 0)
    out[0] = (red[0] + red[1] + red[2] + red[3]) * (1.0f / (float)B);
}

// ---------------------------------------------------------------------------
extern "C" void kernel_launch(void* const* d_in, const int* in_sizes, int n_in,
                              void* d_out, int out_size, void* d_ws, size_t ws_size,
                              hipStream_t stream) {
  const float* x      = (const float*)d_in[0];
  const int*   labels = (const int*)d_in[1];
  float*       out    = (float*)d_out;

  const int B = in_sizes[1];           // 4096
  const int D = in_sizes[0] / B;       // 1024
  const int nblk = B / 128;            // 32

  char* ws = (char*)d_ws;
  uint16_t* xbf = (uint16_t*)ws;       ws += (((size_t)B * D * 2) + 255) & ~(size_t)255;
  uint32_t* gmin = (uint32_t*)ws;      ws += (size_t)B * 4;
  uint32_t* gmax = (uint32_t*)ws;      ws += (size_t)B * 4;
  float* psum_part = (float*)ws;       ws += (size_t)B * nblk * 4;
  float* nsum_part = (float*)ws;       ws += (size_t)B * nblk * 4;
  float* rowbuf = (float*)ws;          ws += (size_t)B * 4;

  hipMemsetAsync(gmin, 0xFF, (size_t)B * 4, stream);
  hipMemsetAsync(gmax, 0x00, (size_t)B * 4, stream);

  const int n = B * D;
  cvt_bf16_kernel<<<n / 1024, 256, 0, stream>>>(x, xbf, n);

  const int nb = nblk * nblk;          // 1024 blocks = 4/CU exact
  {
    const uint16_t* Xp = xbf;
    const int* lp = labels;
    uint32_t* gmn = gmin; uint32_t* gmx = gmax;
    float* pp = psum_part; float* np = nsum_part;
    int Bv = B, Dv = D;
    void* args[] = {(void*)&Xp, (void*)&lp, (void*)&gmn, (void*)&gmx,
                    (void*)&pp, (void*)&np, (void*)&Bv, (void*)&Dv};
    hipError_t err = hipLaunchCooperativeKernel(
        reinterpret_cast<void*>(&msl_kernel<0>), dim3(nb), dim3(256),
        args, 0u, stream);
    if (err != hipSuccess) {
      (void)hipGetLastError();   // clear; fall back to two non-coop passes
      msl_kernel<1><<<nb, 256, 0, stream>>>(xbf, labels, gmin, gmax,
                                            psum_part, nsum_part, B, D);
      msl_kernel<2><<<nb, 256, 0, stream>>>(xbf, labels, gmin, gmax,
                                            psum_part, nsum_part, B, D);
    }
  }

  rowfinal_kernel<<<(B + 255) / 256, 256, 0, stream>>>(gmin, gmax, psum_part,
                                                       nsum_part, rowbuf, B, nblk);
  finalreduce_kernel<<<1, 256, 0, stream>>>(rowbuf, out, B);
}

// Round 5
// 205.419 us; speedup vs baseline: 1.3732x; 1.3732x over previous
//
#include <hip/hip_runtime.h>
#include <hip/hip_bf16.h>
#include <math.h>
#include <stdint.h>

// ---------------------------------------------------------------------------
// MultiSimilarityLoss on MI355X.
//   x: [B=4096, D=1024] fp32 (L2-normalized rows), labels: [B] int32
//   out: scalar fp32 = mean of mined multi-similarity loss
// Pipeline (R6) -- 3 dispatches total:
//   K1: cvt fp32->bf16, fused gmin/gmax/cnt init (block 0)
//   K2: sim = x @ x^T, 528 upper-tri 128x128 tiles, BK=32 double-buffered
//       pipelined (prefetch-before-compute, 1 barrier/iter), T2 swizzle for
//       64B rows, ~34KB LDS -> 4 blocks/CU, NO launch_bounds reg cap.
//       Writes sim + mirror + fused per-row min_pos/max_neg stats.
//   K3: rowloss single pass (stats precomputed), ILP-4 loads, fused
//       rowfinal + last-block deterministic reduce -> out[0].
// R5 post-mortem: __launch_bounds__(256,4) reg cap -> K-loop scratch spills
//   (WRITE +12MB, FETCH +12MB) -> 184us. NEVER cap regs below need.
// R3 lesson: GEMM latency-bound at 2 blocks/CU (66us); BK=32 LDS halving
//   doubles blocks/CU without touching registers (m97 regime).
// ---------------------------------------------------------------------------

#define THRESH    0.5f
#define MARGIN    0.1f
#define SCALE_POS 2.0f
#define SCALE_NEG 40.0f
#define POS_CAP   (1.0f - 1e-5f)

typedef __bf16 bf16x8 __attribute__((ext_vector_type(8)));
typedef float  f32x4  __attribute__((ext_vector_type(4)));

__device__ __forceinline__ uint16_t f2bf(float f) {
  union { float f; uint32_t u; } v; v.f = f;
  uint32_t u = v.u;
  u += 0x7FFFu + ((u >> 16) & 1u);
  return (uint16_t)(u >> 16);
}

__device__ __forceinline__ uint32_t fenc(float f) {
  union { float f; uint32_t u; } v; v.f = f;
  return (v.u & 0x80000000u) ? ~v.u : (v.u ^ 0x80000000u);
}
__device__ __forceinline__ float fdec(uint32_t k) {
  union { float f; uint32_t u; } v;
  v.u = (k & 0x80000000u) ? (k ^ 0x80000000u) : ~k;
  return v.f;
}

// ---- K1: cvt + stat/counter init -------------------------------------------
__global__ __launch_bounds__(256) void cvt_bf16_kernel(
    const float* __restrict__ x, uint16_t* __restrict__ y, int n,
    uint32_t* __restrict__ gmin, uint32_t* __restrict__ gmax,
    uint32_t* __restrict__ cnt, int B) {
  const int tid = threadIdx.x;
  int i = (blockIdx.x * 256 + tid) * 4;
  if (i + 3 < n) {
    float4 v = *(const float4*)(x + i);
    ushort4 o;
    o.x = f2bf(v.x); o.y = f2bf(v.y); o.z = f2bf(v.z); o.w = f2bf(v.w);
    *(ushort4*)(y + i) = o;
  }
  if (blockIdx.x == 0) {
    for (int j = tid; j < B; j += 256) {
      gmin[j] = 0xFFFFFFFFu;
      gmax[j] = 0u;
    }
    if (tid == 0) *cnt = 0u;
  }
}

#if defined(__has_builtin)
#if __has_builtin(__builtin_amdgcn_global_load_lds)
#define HAVE_GLL 1
#endif
#endif

__device__ __forceinline__ void stage16(const uint16_t* g, uint16_t* lds_wave_base, int lane) {
#ifdef HAVE_GLL
  __builtin_amdgcn_global_load_lds(
      (const __attribute__((address_space(1))) void*)g,
      (__attribute__((address_space(3))) void*)lds_wave_base, 16, 0, 0);
#else
  *(uint4*)(lds_wave_base + lane * 8) = *(const uint4*)g;
#endif
}

// ---- K2: sim = X @ X^T, upper-tri tiles, BK=32 pipelined dbuf --------------
__global__ __launch_bounds__(256) void simgemm_kernel(
    const uint16_t* __restrict__ X, const int* __restrict__ labels,
    float* __restrict__ C, uint32_t* __restrict__ gmin, uint32_t* __restrict__ gmax,
    int B, int D) {
  // [buf][A=0/B=1][128 rows][32 cols] bf16 = 32 KiB total
  __shared__ __align__(16) uint16_t sT[2][2][128 * 32];
  __shared__ int slabR[128];
  __shared__ int slabC[128];

  const int nblk = B >> 7;
  const int nb   = nblk * (nblk + 1) / 2;

  // XCD-aware bijective chunk swizzle (nb % 8 == 0 for B=4096)
  int t = blockIdx.x;
  if ((nb & 7) == 0) {
    const int cpx = nb >> 3;
    t = (t % 8) * cpx + t / 8;
  }
  int bi = 0;
  while (t >= nblk - bi) { t -= nblk - bi; ++bi; }
  const int bj = bi + t;
  const int bm = bi * 128;
  const int bn = bj * 128;

  const int tid  = threadIdx.x;
  const int wave = tid >> 6;
  const int lane = tid & 63;
  const int waveM = wave >> 1, waveN = wave & 1;

  if (tid < 128) slabR[tid] = labels[bm + tid];
  else           slabC[tid - 128] = labels[bn + tid - 128];

  const uint16_t* gA = X + (size_t)bm * D;
  const uint16_t* gB = X + (size_t)bn * D;

  // staging map: 16B-chunk idx = s*256 + tid (s=0,1); row = idx>>2 (64B rows)
  // inverse-swizzled global byte-in-row = ((idx&3)<<4) ^ ((row&3)<<4)
  int srcOff[2];
#pragma unroll
  for (int s = 0; s < 2; ++s) {
    const int idx = s * 256 + tid;
    const int row = idx >> 2;
    const int cb  = ((idx & 3) << 4) ^ ((row & 3) << 4);
    srcOff[s] = row * D + (cb >> 1);
  }

  const int fr = lane & 15;
  const int fq = lane >> 4;
  const int sw = (fr & 3) << 4;   // read swizzle: row&3 == fr&3 (rows stride 16/64)

  f32x4 acc[4][4] = {};

  const int NT = D >> 5;          // 32 K-tiles of 32

  // prologue: stage tile 0 into buf 0 (per wave: 2 gll A + 2 gll B)
#pragma unroll
  for (int s = 0; s < 2; ++s) {
    uint16_t* dA = &sT[0][0][0] + (s * 256 + wave * 64) * 8;
    uint16_t* dB = &sT[0][1][0] + (s * 256 + wave * 64) * 8;
    stage16(gA + srcOff[s], dA, lane);
    stage16(gB + srcOff[s], dB, lane);
  }
  __syncthreads();

  int cur = 0;
  for (int kt = 0; kt < NT; ++kt) {
    if (kt + 1 < NT) {
      const int k0 = (kt + 1) << 5;
#pragma unroll
      for (int s = 0; s < 2; ++s) {
        uint16_t* dA = &sT[cur ^ 1][0][0] + (s * 256 + wave * 64) * 8;
        uint16_t* dB = &sT[cur ^ 1][1][0] + (s * 256 + wave * 64) * 8;
        stage16(gA + srcOff[s] + k0, dA, lane);
        stage16(gB + srcOff[s] + k0, dB, lane);
      }
    }

    const char* tA = (const char*)&sT[cur][0][0];
    const char* tB = (const char*)&sT[cur][1][0];
    const int cbyte = (fq * 16) ^ sw;
    bf16x8 af[4], bfv[4];
#pragma unroll
    for (int mt = 0; mt < 4; ++mt) {
      const int rowa = waveM * 64 + mt * 16 + fr;
      af[mt] = *(const bf16x8*)(tA + rowa * 64 + cbyte);
    }
#pragma unroll
    for (int nt = 0; nt < 4; ++nt) {
      const int rowb = waveN * 64 + nt * 16 + fr;
      bfv[nt] = *(const bf16x8*)(tB + rowb * 64 + cbyte);
    }
#pragma unroll
    for (int mt = 0; mt < 4; ++mt)
#pragma unroll
      for (int nt = 0; nt < 4; ++nt)
        acc[mt][nt] = __builtin_amdgcn_mfma_f32_16x16x32_bf16(
            af[mt], bfv[nt], acc[mt][nt], 0, 0, 0);

    __syncthreads();   // prefetch landed (vmcnt drain) + LDS reads done
    cur ^= 1;
  }

  // ---- direct write C[bm..][bn..] -----------------------------------------
#pragma unroll
  for (int mt = 0; mt < 4; ++mt) {
#pragma unroll
    for (int nt = 0; nt < 4; ++nt) {
      const int col = bn + waveN * 64 + nt * 16 + fr;
#pragma unroll
      for (int r = 0; r < 4; ++r) {
        const int row = bm + waveM * 64 + mt * 16 + fq * 4 + r;
        C[(size_t)row * B + col] = acc[mt][nt][r];
      }
    }
  }

  // ---- mirror write C[bn..][bm..] = tile^T --------------------------------
  if (bi != bj) {
#pragma unroll
    for (int mt = 0; mt < 4; ++mt) {
#pragma unroll
      for (int nt = 0; nt < 4; ++nt) {
        const int col  = bn + waveN * 64 + nt * 16 + fr;
        const int rowb = bm + waveM * 64 + mt * 16 + fq * 4;
        *(f32x4*)(C + (size_t)col * B + rowb) = acc[mt][nt];
      }
    }
  }

  // ---- per-row stats: min positive (valid), max negative ------------------
  const float INF = __builtin_inff();

  int lr[4][4];
#pragma unroll
  for (int mt = 0; mt < 4; ++mt)
#pragma unroll
    for (int r = 0; r < 4; ++r)
      lr[mt][r] = slabR[waveM * 64 + mt * 16 + fq * 4 + r];
  int lc[4];
#pragma unroll
  for (int nt = 0; nt < 4; ++nt) lc[nt] = slabC[waveN * 64 + nt * 16 + fr];

  {
    float rmin[4][4], rmax[4][4];
#pragma unroll
    for (int mt = 0; mt < 4; ++mt)
#pragma unroll
      for (int r = 0; r < 4; ++r) { rmin[mt][r] = INF; rmax[mt][r] = -INF; }

#pragma unroll
    for (int mt = 0; mt < 4; ++mt) {
#pragma unroll
      for (int nt = 0; nt < 4; ++nt) {
        const int gcol = bn + waveN * 64 + nt * 16 + fr;
#pragma unroll
        for (int r = 0; r < 4; ++r) {
          const int grow = bm + waveM * 64 + mt * 16 + fq * 4 + r;
          const float s = acc[mt][nt][r];
          if (lr[mt][r] == lc[nt]) {
            if (grow != gcol && s < POS_CAP) rmin[mt][r] = fminf(rmin[mt][r], s);
          } else {
            rmax[mt][r] = fmaxf(rmax[mt][r], s);
          }
        }
      }
    }
#pragma unroll
    for (int mt = 0; mt < 4; ++mt)
#pragma unroll
      for (int r = 0; r < 4; ++r) {
#pragma unroll
        for (int m = 1; m < 16; m <<= 1) {
          rmin[mt][r] = fminf(rmin[mt][r], __shfl_xor(rmin[mt][r], m, 64));
          rmax[mt][r] = fmaxf(rmax[mt][r], __shfl_xor(rmax[mt][r], m, 64));
        }
      }
    if (fr == 0) {
#pragma unroll
      for (int mt = 0; mt < 4; ++mt)
#pragma unroll
        for (int r = 0; r < 4; ++r) {
          const int grow = bm + waveM * 64 + mt * 16 + fq * 4 + r;
          if (rmin[mt][r] < INF)  atomicMin(&gmin[grow], fenc(rmin[mt][r]));
          if (rmax[mt][r] > -INF) atomicMax(&gmax[grow], fenc(rmax[mt][r]));
        }
    }
  }

  if (bi != bj) {
    float cmin[4], cmax[4];
#pragma unroll
    for (int nt = 0; nt < 4; ++nt) { cmin[nt] = INF; cmax[nt] = -INF; }
#pragma unroll
    for (int nt = 0; nt < 4; ++nt) {
      const int gcol = bn + waveN * 64 + nt * 16 + fr;
#pragma unroll
      for (int mt = 0; mt < 4; ++mt) {
#pragma unroll
        for (int r = 0; r < 4; ++r) {
          const int grow = bm + waveM * 64 + mt * 16 + fq * 4 + r;
          const float s = acc[mt][nt][r];
          if (lc[nt] == lr[mt][r]) {
            if (grow != gcol && s < POS_CAP) cmin[nt] = fminf(cmin[nt], s);
          } else {
            cmax[nt] = fmaxf(cmax[nt], s);
          }
        }
      }
    }
#pragma unroll
    for (int nt = 0; nt < 4; ++nt) {
#pragma unroll
      for (int m = 16; m < 64; m <<= 1) {
        cmin[nt] = fminf(cmin[nt], __shfl_xor(cmin[nt], m, 64));
        cmax[nt] = fmaxf(cmax[nt], __shfl_xor(cmax[nt], m, 64));
      }
    }
    if (fq == 0) {
#pragma unroll
      for (int nt = 0; nt < 4; ++nt) {
        const int gcol = bn + waveN * 64 + nt * 16 + fr;
        if (cmin[nt] < INF)  atomicMin(&gmin[gcol], fenc(cmin[nt]));
        if (cmax[nt] > -INF) atomicMax(&gmax[gcol], fenc(cmax[nt]));
      }
    }
  }
}

// ---- K3: rowloss (single pass, ILP-4) + fused final reduce -----------------
__global__ __launch_bounds__(256) void rowloss_kernel(
    const float* __restrict__ sim, const int* __restrict__ labels,
    const uint32_t* __restrict__ gmin, const uint32_t* __restrict__ gmax,
    float* __restrict__ rowbuf, float* __restrict__ out,
    uint32_t* __restrict__ cnt, int B) {
  __shared__ int   slab[4096];
  __shared__ float red[4][8];
  __shared__ float fred[4];
  __shared__ int   isLast;

  const int tid  = threadIdx.x;
  const int wave = tid >> 6;
  const int lane = tid & 63;
  const float INF = __builtin_inff();

  for (int tq = tid; tq < (B >> 2); tq += 256)
    ((int4*)slab)[tq] = ((const int4*)labels)[tq];
  __syncthreads();

  const int i0 = blockIdx.x * 4;

  float minpos[4], maxneg[4];
  bool  haspos[4], hasneg[4];
  int   li[4];
#pragma unroll
  for (int r = 0; r < 4; ++r) {
    const uint32_t km = gmin[i0 + r], kx = gmax[i0 + r];
    haspos[r] = (km != 0xFFFFFFFFu);
    hasneg[r] = (kx != 0u);
    minpos[r] = haspos[r] ? fdec(km) : INF;
    maxneg[r] = hasneg[r] ? fdec(kx) : -INF;
    li[r] = slab[i0 + r];
  }

  float ps[4] = {}, ns[4] = {};
  const int iters = B >> 10;   // 4 col-chunks of 1024
  for (int it = 0; it < iters; ++it) {
    const int j = it * 1024 + tid * 4;
    float4 v[4];
#pragma unroll
    for (int r = 0; r < 4; ++r)    // 4 independent loads -> ILP
      v[r] = *(const float4*)(sim + (size_t)(i0 + r) * B + j);
#pragma unroll
    for (int r = 0; r < 4; ++r) {
      const int i = i0 + r;
      float s4[4] = {v[r].x, v[r].y, v[r].z, v[r].w};
#pragma unroll
      for (int q = 0; q < 4; ++q) {
        const int jj = j + q;
        const float s = s4[q];
        if (slab[jj] == li[r]) {
          if (jj != i && s < POS_CAP && (s - MARGIN < maxneg[r]))
            ps[r] += __expf(-SCALE_POS * (s - THRESH));
        } else {
          if (s + MARGIN > minpos[r])
            ns[r] += __expf(SCALE_NEG * (s - THRESH));
        }
      }
    }
  }

  // wave-level reduce (same order as R3: xor 32..1 per value)
#pragma unroll
  for (int r = 0; r < 4; ++r) {
#pragma unroll
    for (int m = 32; m > 0; m >>= 1) {
      ps[r] += __shfl_xor(ps[r], m, 64);
      ns[r] += __shfl_xor(ns[r], m, 64);
    }
  }
  if (lane == 0) {
#pragma unroll
    for (int r = 0; r < 4; ++r) { red[wave][r] = ps[r]; red[wave][4 + r] = ns[r]; }
  }
  __syncthreads();

  if (tid < 4) {   // one thread per row: combine waves in fixed order
    const int r = tid;
    const float P = red[0][r] + red[1][r] + red[2][r] + red[3][r];
    const float N = red[0][4 + r] + red[1][4 + r] + red[2][4 + r] + red[3][4 + r];
    const bool has_row = haspos[r] && hasneg[r] && (P > 0.f) && (N > 0.f);
    rowbuf[i0 + r] = has_row
        ? (log1pf(P) * (1.0f / SCALE_POS) + log1pf(N) * (1.0f / SCALE_NEG))
        : 0.f;
  }
  __threadfence();
  __syncthreads();

  if (tid == 0) {
    const uint32_t v = atomicAdd(cnt, 1u);
    isLast = (v == (uint32_t)(gridDim.x - 1)) ? 1 : 0;
  }
  __syncthreads();

  if (isLast) {
    __threadfence();   // acquire: make all blocks' rowbuf stores visible
    float s = 0.f;
    for (int j = tid * 4; j < B; j += 1024) {
      float4 v = *(const float4*)(rowbuf + j);
      s += v.x + v.y + v.z + v.w;
    }
#pragma unroll
    for (int m = 32; m > 0; m >>= 1) s += __shfl_xor(s, m, 64);
    if (lane == 0) fred[wave] = s;
    __syncthreads();
    if (tid == 0)
      out[0] = (fred[0] + fred[1] + fred[2] + fred[3]) * (1.0f / (float)B);
  }
}

// ---------------------------------------------------------------------------
extern "C" void kernel_launch(void* const* d_in, const int* in_sizes, int n_in,
                              void* d_out, int out_size, void* d_ws, size_t ws_size,
                              hipStream_t stream) {
  const float* x      = (const float*)d_in[0];
  const int*   labels = (const int*)d_in[1];
  float*       out    = (float*)d_out;

  const int B = in_sizes[1];           // 4096
  const int D = in_sizes[0] / B;       // 1024

  char* ws = (char*)d_ws;
  uint16_t* xbf = (uint16_t*)ws;       ws += (((size_t)B * D * 2) + 255) & ~(size_t)255;
  float* sim = (float*)ws;             ws += (size_t)B * B * 4;
  uint32_t* gmin = (uint32_t*)ws;      ws += (size_t)B * 4;
  uint32_t* gmax = (uint32_t*)ws;      ws += (size_t)B * 4;
  float* rowbuf = (float*)ws;          ws += (size_t)B * 4;
  uint32_t* cnt = (uint32_t*)ws;       ws += 256;

  const int n = B * D;
  cvt_bf16_kernel<<<n / 1024, 256, 0, stream>>>(x, xbf, n, gmin, gmax, cnt, B);

  const int nblk = B / 128;
  const int nb   = nblk * (nblk + 1) / 2;   // 528 upper-triangle tiles
  simgemm_kernel<<<nb, 256, 0, stream>>>(xbf, labels, sim, gmin, gmax, B, D);

  rowloss_kernel<<<B / 4, 256, 0, stream>>>(sim, labels, gmin, gmax,
                                            rowbuf, out, cnt, B);
}